// Round 6
// baseline (3760.442 us; speedup 1.0000x reference)
//
#include <hip/hip_runtime.h>
#include <hip/hip_bf16.h>
#include <math.h>

#define BTOT   16384
#define NLAYER 24
#define HID    192
#define NDIN   12
#define NBASE  66
#define EPSP   1e-3f
#define EPB    32        // elements per block -> grid 512 -> 2 blocks/CU

// ---------------- LDS layout (bytes), 41,248 total ----------------
#define EST 200          // k/j stride (shorts) for sH1b/sGb rows
#define OB_H1  0         // ushort[32*200] 12800 : h1 bf16 [e][k]
#define OB_G   12800     // ushort[32*200] 12800 : h2 then G bf16 [e][j]
#define OB_R   25600     // float[72*32]    9216 : cotangent rows [rt][e]
#define OB_W1  34816     // ushort[192*8]   3072 : W1 bf16 rows padded to 8
#define OB_PRM 37888     // float[12*32]    1536 : prm sums; then tf@2i, es@2i+1
#define OB_GZ  39424     // float[6*32]      768 : g_z1 partials (atomics)
#define OB_Z1  40192     // float[6*32]      768 : z[6..12) for next F1
#define OB_LD  40960     // float[32]        128 : logdet acc
#define OB_ZQ  41088     // float[32]        128 : sum z^2
#define OB_RED 41216     // float[8]          32
#define SMEM_BYTES 41248

typedef __attribute__((ext_vector_type(8))) short s8v;
typedef __attribute__((ext_vector_type(4))) float f4v;
#define MFMA16(a,b,c) __builtin_amdgcn_mfma_f32_16x16x32_bf16(a,b,c,0,0,0)

__device__ __forceinline__ unsigned short f2bf(float f) {
  unsigned u = __builtin_bit_cast(unsigned, f);
  u += 0x7fffu + ((u >> 16) & 1u);          // RNE
  return (unsigned short)(u >> 16);
}
__device__ __forceinline__ float bf2f(unsigned short h) {
  unsigned u = ((unsigned)h) << 16;
  return __builtin_bit_cast(float, u);
}
__device__ __forceinline__ unsigned pk2(float a, float b) {
  return (unsigned)f2bf(a) | ((unsigned)f2bf(b) << 16);
}

// ---------------------------------------------------------------------
// prep: W2 -> bf16 (orig layout) and bf16 transpose, into workspace.
__global__ void prep_kernel(const float* __restrict__ W2,
                            unsigned short* __restrict__ w2b,
                            unsigned short* __restrict__ w2t) {
  int idx = blockIdx.x * 256 + threadIdx.x;   // 884736 exact
  int l   = idx / (HID * HID);
  int rem = idx - l * HID * HID;
  int k   = rem / HID;
  int j   = rem - k * HID;
  w2b[idx] = f2bf(W2[idx]);                         // [l][j][k]
  w2t[idx] = f2bf(W2[l * HID * HID + j * HID + k]); // [l][k][j]
}

// ---------------------------------------------------------------------
// flow_kernel: block = 32 elements, 512 threads (8 waves), grid 512.
// Scalar phases: e = tid&31, slab = tid>>5 (12 rows each).
// MFMA phases: 12 m-tiles x 2 n-tiles; wave w -> mtg=(w>>1)*3, ntg=w&1.
// NOTE __launch_bounds__ 2nd arg acts as CUDA minBlocks on this compiler
// (R5 evidence: (512,4) -> 64-VGPR cap + 291MB spill). (512,2) -> 128 cap.
__global__ __launch_bounds__(512, 2) void flow_kernel(
    float* __restrict__ yz, float* __restrict__ jp,
    const float* __restrict__ W1, const float* __restrict__ b1,
    const float* __restrict__ b2,
    const float* __restrict__ W3, const float* __restrict__ b3,
    const unsigned short* __restrict__ w2b,
    const unsigned short* __restrict__ w2t,
    float* __restrict__ ws_sum, float* __restrict__ out_lp) {
  extern __shared__ char smraw[];
  unsigned short* sH1b = (unsigned short*)(smraw + OB_H1);
  unsigned short* sGb  = (unsigned short*)(smraw + OB_G);
  float* sR   = (float*)(smraw + OB_R);
  float* sPRM = (float*)(smraw + OB_PRM);
  float* sGZ  = (float*)(smraw + OB_GZ);
  float* sZ1  = (float*)(smraw + OB_Z1);
  float* sLD  = (float*)(smraw + OB_LD);
  float* sZQ  = (float*)(smraw + OB_ZQ);
  float* sRed = (float*)(smraw + OB_RED);

  const int tid  = threadIdx.x;
  const int lane = tid & 63;
  const int w    = __builtin_amdgcn_readfirstlane(tid >> 6);
  const int e    = tid & 31;                     // element (scalar phases)
  const int jb   = (tid >> 5) * 12;              // 12-row slab
  const int lm   = lane & 15, lq = lane >> 4;    // MFMA lane coords
  const int mtg  = (w >> 1) * 3;                 // m-tile base (0,3,6,9)
  const int ntg  = w & 1;                        // n-tile (0..1)
  const int blk  = blockIdx.x;

  // ---- init ----
  float z_a = 0.f, z_b = 0.f;     // z[i], z[6+i] held by tid<192 (i=tid>>5)
  if (tid < 192) {
    int i = tid >> 5;
    z_a = yz[(blk * EPB + e) * 12 + i];
    z_b = yz[(blk * EPB + e) * 12 + 6 + i];
    sZ1[i * EPB + e] = z_b;
    sGZ[i * EPB + e] = 0.f;
  }
  if (tid < 32) { sLD[tid] = 0.f; sZQ[tid] = 0.f; }
  if (tid == 0) sRed[0] = 0.f;
  for (int idx = tid; idx < 72 * EPB; idx += 512) {
    int rt = idx >> 5, ee = idx & 31;
    sR[idx] = jp[(blk * EPB + ee) * 72 + rt];
  }
  __syncthreads();

  unsigned m2 = 0;   // 12-bit relu mask for this thread's h2 slab

  for (int l = NLAYER - 1; l >= 0; --l) {
    const float* W1l = W1 + l * HID * 6;
    const float* b1l = b1 + l * HID;
    const float* b2l = b2 + l * HID;
    const float* W3l = W3 + l * NDIN * HID;
    const float* b3l = b3 + l * NDIN;
    const unsigned short* w2bl = w2b + l * HID * HID;
    const unsigned short* w2tl = w2t + l * HID * HID;

    // ======== F1: stage W1 bf16, zero sPRM, h1 = relu(W1 z1 + b1) ========
    if (tid < 192) {
      const float* wr = W1l + tid * 6;
      uint4 pk;
      pk.x = pk2(wr[0], wr[1]); pk.y = pk2(wr[2], wr[3]);
      pk.z = pk2(wr[4], wr[5]); pk.w = 0;
      *(uint4*)(smraw + OB_W1 + tid * 16) = pk;
    }
    if (tid < 384) sPRM[tid] = 0.f;
    {
      float z1v[6];
      #pragma unroll
      for (int i = 0; i < 6; ++i) z1v[i] = sZ1[i * EPB + e];
      #pragma unroll
      for (int jj = 0; jj < 12; ++jj) {
        int j = jb + jj;
        float acc = b1l[j];
        #pragma unroll
        for (int i = 0; i < 6; ++i) acc = fmaf(W1l[j * 6 + i], z1v[i], acc);
        sH1b[e * EST + j] = f2bf(fmaxf(acc, 0.f));
      }
    }
    __syncthreads();

    // ======== S1: F2 via MFMA: h2 = relu(W2 h1 + b2) -> sGb[e][j] ========
    {
      f4v acc3[3] = {{0,0,0,0},{0,0,0,0},{0,0,0,0}};
      #pragma unroll
      for (int kk = 0; kk < 6; ++kk) {
        int jo = kk * 32 + lq * 8;
        s8v B = *(const s8v*)&sH1b[(ntg * 16 + lm) * EST + jo];
        #pragma unroll
        for (int p = 0; p < 3; ++p) {
          s8v A = *(const s8v*)(w2bl + ((mtg + p) * 16 + lm) * HID + jo);
          acc3[p] = MFMA16(A, B, acc3[p]);
        }
      }
      int e2 = ntg * 16 + lm;
      #pragma unroll
      for (int p = 0; p < 3; ++p) {
        int jb2 = (mtg + p) * 16 + lq * 4;
        float h0 = fmaxf(acc3[p][0] + b2l[jb2],     0.f);
        float h1 = fmaxf(acc3[p][1] + b2l[jb2 + 1], 0.f);
        float h2 = fmaxf(acc3[p][2] + b2l[jb2 + 2], 0.f);
        float h3 = fmaxf(acc3[p][3] + b2l[jb2 + 3], 0.f);
        unsigned* dst = (unsigned*)sGb + ((e2 * EST + jb2) >> 1);
        dst[0] = pk2(h0, h1);
        dst[1] = pk2(h2, h3);
      }
    }
    __syncthreads();

    // ======== S2: prm partials from h2 slab + capture mask2 ==============
    {
      const unsigned* hp = (const unsigned*)&sGb[e * EST + jb];
      float h2v[12];
      m2 = 0;
      #pragma unroll
      for (int c = 0; c < 6; ++c) {
        unsigned hu = hp[c];
        unsigned short b0 = (unsigned short)(hu & 0xffff);
        unsigned short b1v = (unsigned short)(hu >> 16);
        h2v[2 * c]     = bf2f(b0);
        h2v[2 * c + 1] = bf2f(b1v);
        m2 |= (b0 != 0 ? 1u : 0u) << (2 * c);
        m2 |= (b1v != 0 ? 1u : 0u) << (2 * c + 1);
      }
      #pragma unroll
      for (int t = 0; t < 12; ++t) {
        const float* w3r = W3l + t * HID + jb;
        float pp = 0.f;
        #pragma unroll
        for (int jj = 0; jj < 12; ++jj) pp = fmaf(w3r[jj], h2v[jj], pp);
        atomicAdd(&sPRM[t * EPB + e], pp);
      }
    }
    __syncthreads();

    // ======== U: coupling update; sPRM becomes tf@(2i), es@(2i+1) ========
    if (tid < 192) {
      int i = tid >> 5;
      float sh = b3l[2 * i]     + sPRM[(2 * i) * EPB + e];
      float sr = b3l[2 * i + 1] + sPRM[(2 * i + 1) * EPB + e];
      float s  = 2.f * tanhf(0.5f * sr);
      float es = expf(s), en = expf(-s);
      float tv = z_a - sh;
      z_a = z_b;
      z_b = tv * en;
      sZ1[i * EPB + e] = z_b;
      sPRM[(2 * i) * EPB + e]     = tv * (1.f - 0.25f * s * s);  // tf
      sPRM[(2 * i + 1) * EPB + e] = es;                          // es
      atomicAdd(&sLD[e], -s);
    }
    __syncthreads();

    #define DO_V2(rr)                                                        \
    {                                                                        \
      float gp[12];                                                          \
      _Pragma("unroll")                                                      \
      for (int i = 0; i < 6; ++i) {                                          \
        float r1 = sR[((rr) * 12 + i) * EPB + e];                            \
        gp[2 * i]     = r1;                                                  \
        gp[2 * i + 1] = r1 * sPRM[(2 * i) * EPB + e];                        \
      }                                                                      \
      float g[12];                                                           \
      _Pragma("unroll")                                                      \
      for (int jj = 0; jj < 12; ++jj) g[jj] = 0.f;                           \
      _Pragma("unroll")                                                      \
      for (int t = 0; t < 12; ++t) {                                         \
        const float* w3r = W3l + t * HID + jb;                               \
        _Pragma("unroll")                                                    \
        for (int jj = 0; jj < 12; ++jj) g[jj] = fmaf(w3r[jj], gp[t], g[jj]); \
      }                                                                      \
      unsigned* dst = (unsigned*)sGb + ((e * EST + jb) >> 1);                \
      _Pragma("unroll")                                                      \
      for (int pr = 0; pr < 6; ++pr) {                                       \
        int jj = 2 * pr;                                                     \
        float v0 = ((m2 >> jj) & 1) ? g[jj] : 0.f;                           \
        float v1 = ((m2 >> (jj + 1)) & 1) ? g[jj + 1] : 0.f;                 \
        dst[pr] = pk2(v0, v1);                                               \
      }                                                                      \
    }

    DO_V2(0);
    __syncthreads();

    for (int r = 0; r < 6; ++r) {
      // ---- V3 MFMA + epilogue: mask1, W1^T, sGZ atomics ----
      {
        f4v acc3[3] = {{0,0,0,0},{0,0,0,0},{0,0,0,0}};
        #pragma unroll
        for (int kk = 0; kk < 6; ++kk) {
          int jo = kk * 32 + lq * 8;
          s8v B = *(const s8v*)&sGb[(ntg * 16 + lm) * EST + jo];
          #pragma unroll
          for (int p = 0; p < 3; ++p) {
            s8v A = *(const s8v*)(w2tl + ((mtg + p) * 16 + lm) * HID + jo);
            acc3[p] = MFMA16(A, B, acc3[p]);
          }
        }
        int e2 = ntg * 16 + lm;
        float pz[6] = {0.f, 0.f, 0.f, 0.f, 0.f, 0.f};
        #pragma unroll
        for (int p = 0; p < 3; ++p) {
          int kb = (mtg + p) * 16 + lq * 4;
          const unsigned* mp = (const unsigned*)&sH1b[e2 * EST + kb];
          unsigned mm0 = mp[0], mm1 = mp[1];
          unsigned short hb[4] = {
            (unsigned short)(mm0 & 0xffff), (unsigned short)(mm0 >> 16),
            (unsigned short)(mm1 & 0xffff), (unsigned short)(mm1 >> 16)};
          #pragma unroll
          for (int rg = 0; rg < 4; ++rg) {
            float val = hb[rg] ? acc3[p][rg] : 0.f;
            uint4 wr = *(const uint4*)(smraw + OB_W1 + (kb + rg) * 16);
            pz[0] = fmaf(bf2f((unsigned short)(wr.x & 0xffff)), val, pz[0]);
            pz[1] = fmaf(bf2f((unsigned short)(wr.x >> 16)),    val, pz[1]);
            pz[2] = fmaf(bf2f((unsigned short)(wr.y & 0xffff)), val, pz[2]);
            pz[3] = fmaf(bf2f((unsigned short)(wr.y >> 16)),    val, pz[3]);
            pz[4] = fmaf(bf2f((unsigned short)(wr.z & 0xffff)), val, pz[4]);
            pz[5] = fmaf(bf2f((unsigned short)(wr.z >> 16)),    val, pz[5]);
          }
        }
        #pragma unroll
        for (int i = 0; i < 6; ++i)
          atomicAdd(&sGZ[i * EPB + e2], pz[i]);
      }
      __syncthreads();

      // ---- V5 (cotangent row r) + V2 of next row ----
      if (tid < 192) {
        int i = tid >> 5;
        float r1  = sR[(r * 12 + i) * EPB + e];
        float r2o = sR[(r * 12 + 6 + i) * EPB + e];
        float es  = sPRM[(2 * i + 1) * EPB + e];
        sR[(r * 12 + i) * EPB + e]     = r2o + sGZ[i * EPB + e];
        sR[(r * 12 + 6 + i) * EPB + e] = r1 * es;
        sGZ[i * EPB + e] = 0.f;
      }
      if (r < 5) { DO_V2(r + 1); }
      __syncthreads();
    }
    #undef DO_V2
  }

  // ---- epilogue ----
  if (tid < 192) {
    int i = tid >> 5;
    yz[(blk * EPB + e) * 12 + i]     = z_a;
    yz[(blk * EPB + e) * 12 + 6 + i] = z_b;
    atomicAdd(&sZQ[e], fmaf(z_a, z_a, z_b * z_b));
  }
  __syncthreads();
  if (tid < 32)
    out_lp[blk * EPB + tid] = sLD[tid] - 11.027262398456072f - 0.5f * sZQ[tid];

  float part = 0.f;
  for (int idx = tid; idx < 72 * EPB; idx += 512) {
    int rt = idx >> 5, ee = idx & 31;
    float v = sR[idx];
    jp[(blk * EPB + ee) * 72 + rt] = v;
    part = fmaf(v, v, part);
  }
  #pragma unroll
  for (int off = 32; off > 0; off >>= 1) part += __shfl_down(part, off, 64);
  if ((tid & 63) == 0) atomicAdd(&sRed[0], part);
  __syncthreads();
  if (tid == 0) atomicAdd(ws_sum, sRed[0]);
}

// ---------------------------------------------------------------------
// kl_kernel: one thread per element (unchanged from R3/R4/R5 PASS).
__global__ __launch_bounds__(256) void kl_kernel(
    const float* __restrict__ zin, const float* __restrict__ jpin,
    const float* __restrict__ Wsym, const float* __restrict__ lvd,
    const float* __restrict__ ws_sum, float* __restrict__ out_kl) {
  int elem = blockIdx.x * 256 + threadIdx.x;
  float z[12];
  #pragma unroll
  for (int i = 0; i < 12; ++i) z[i] = zin[elem * 12 + i];
  float scale = 1.0f / sqrtf(ws_sum[0]);
  float Jp[6][12];
  #pragma unroll
  for (int n = 0; n < 6; ++n)
    #pragma unroll
    for (int j = 0; j < 12; ++j)
      Jp[n][j] = jpin[elem * 72 + n * 12 + j] * scale;

  float Sq[78];
  #pragma unroll
  for (int i = 0; i < 78; ++i) Sq[i] = 0.f;
  float tq = 0.f, tpq = 0.f;

  for (int m = 0; m < NBASE; ++m) {
    const float* Wm = Wsym + m * 144;
    float jq[12];
    #pragma unroll
    for (int j = 0; j < 12; ++j) {
      float acc = 0.f;
      #pragma unroll
      for (int i = 0; i < 12; ++i)
        acc = fmaf(Wm[j * 12 + i] - Wm[i * 12 + j], z[i], acc);
      jq[j] = acc;
    }
    #pragma unroll
    for (int i = 0; i < 12; ++i) {
      tq = fmaf(jq[i], jq[i], tq);
      #pragma unroll
      for (int j = 0; j <= i; ++j)
        Sq[i * (i + 1) / 2 + j] = fmaf(jq[i], jq[j], Sq[i * (i + 1) / 2 + j]);
    }
    #pragma unroll
    for (int n = 0; n < 6; ++n) {
      float d = 0.f;
      #pragma unroll
      for (int j = 0; j < 12; ++j) d = fmaf(Jp[n][j], jq[j], d);
      tpq = fmaf(d, d, tpq);
    }
  }

  float Dv[12], Db[12];
  #pragma unroll
  for (int j = 0; j < 12; ++j) Dv[j] = expf(-lvd[j]);

  float mh = 0.f;
  #pragma unroll
  for (int i = 0; i < 12; ++i) mh += Sq[i * (i + 1) / 2 + i] + Dv[i];
  float norm_H = fmaxf(mh * (1.f / 12.f), 1e-6f);
  #pragma unroll
  for (int i = 0; i < 12; ++i) Sq[i * (i + 1) / 2 + i] += Dv[i] + 1e-3f * norm_H;
  float sumDb = 0.f;
  #pragma unroll
  for (int j = 0; j < 12; ++j) { Db[j] = Dv[j] + 1e-3f * norm_H; sumDb += Db[j]; }

  float M[21];
  #pragma unroll
  for (int n = 0; n < 6; ++n)
    #pragma unroll
    for (int mm = 0; mm <= n; ++mm) {
      float acc = 0.f;
      #pragma unroll
      for (int j = 0; j < 12; ++j) acc = fmaf(Jp[n][j], Jp[mm][j], acc);
      M[n * (n + 1) / 2 + mm] = acc;
    }
  float md = 0.f;
  #pragma unroll
  for (int i = 0; i < 6; ++i) md += M[i * (i + 1) / 2 + i];
  float norm_M = fmaxf(md * (1.f / 6.f) + EPSP, 1e-6f);
  #pragma unroll
  for (int i = 0; i < 6; ++i) M[i * (i + 1) / 2 + i] += EPSP + 1e-3f * norm_M;

  float trace_p = 0.f;
  #pragma unroll
  for (int n = 0; n < 6; ++n)
    #pragma unroll
    for (int j = 0; j < 12; ++j)
      trace_p = fmaf(Jp[n][j] * Jp[n][j], Db[j], trace_p);

  float trace = (EPSP + 1e-3f * norm_M) * (sumDb + tq) + trace_p + tpq;

  float ldM = 0.f;
  #pragma unroll
  for (int jc = 0; jc < 6; ++jc) {
    float d = M[jc * (jc + 1) / 2 + jc];
    #pragma unroll
    for (int k = 0; k < jc; ++k) d -= M[jc * (jc + 1) / 2 + k] * M[jc * (jc + 1) / 2 + k];
    d = sqrtf(d);
    ldM += logf(d);
    float di = 1.f / d;
    M[jc * (jc + 1) / 2 + jc] = d;
    #pragma unroll
    for (int i2 = jc + 1; i2 < 6; ++i2) {
      float v = M[i2 * (i2 + 1) / 2 + jc];
      #pragma unroll
      for (int k = 0; k < jc; ++k) v -= M[i2 * (i2 + 1) / 2 + k] * M[jc * (jc + 1) / 2 + k];
      M[i2 * (i2 + 1) / 2 + jc] = v * di;
    }
  }

  float ldH = 0.f;
  #pragma unroll
  for (int jc = 0; jc < 12; ++jc) {
    float d = Sq[jc * (jc + 1) / 2 + jc];
    #pragma unroll
    for (int k = 0; k < jc; ++k) d -= Sq[jc * (jc + 1) / 2 + k] * Sq[jc * (jc + 1) / 2 + k];
    d = sqrtf(d);
    ldH += logf(d);
    float di = 1.f / d;
    Sq[jc * (jc + 1) / 2 + jc] = d;
    #pragma unroll
    for (int i2 = jc + 1; i2 < 12; ++i2) {
      float v = Sq[i2 * (i2 + 1) / 2 + jc];
      #pragma unroll
      for (int k = 0; k < jc; ++k) v -= Sq[i2 * (i2 + 1) / 2 + k] * Sq[jc * (jc + 1) / 2 + k];
      Sq[i2 * (i2 + 1) / 2 + jc] = v * di;
    }
  }

  float logdet_p = 2.f * ldM + 6.f * logf(EPSP);
  float logdet_q = 2.f * ldH;
  out_kl[elem] = 0.5f * (trace - (logdet_p + logdet_q) - 12.f);
}

// ---------------------------------------------------------------------
extern "C" void kernel_launch(void* const* d_in, const int* in_sizes, int n_in,
                              void* d_out, int out_size, void* d_ws, size_t ws_size,
                              hipStream_t stream) {
  (void)in_sizes; (void)n_in; (void)out_size; (void)ws_size;
  float* y    = (float*)d_in[0];   // consumed, then overwritten with z
  float* Jp   = (float*)d_in[1];   // consumed, then overwritten with pullback Jp
  const float* W1   = (const float*)d_in[2];
  const float* b1   = (const float*)d_in[3];
  const float* W2   = (const float*)d_in[4];
  const float* b2   = (const float*)d_in[5];
  const float* W3   = (const float*)d_in[6];
  const float* b3   = (const float*)d_in[7];
  const float* Wsym = (const float*)d_in[8];
  const float* lvd  = (const float*)d_in[9];
  float* out = (float*)d_out;      // fp32: [log_prob (B), kl (B)]

  float* ws_sum = (float*)d_ws;
  unsigned short* w2b = (unsigned short*)((char*)d_ws + 256);
  unsigned short* w2t = (unsigned short*)((char*)d_ws + 256 +
                                          NLAYER * HID * HID * 2);
  hipMemsetAsync(d_ws, 0, 4, stream);

  hipFuncSetAttribute((const void*)flow_kernel,
                      hipFuncAttributeMaxDynamicSharedMemorySize, SMEM_BYTES);

  prep_kernel<<<3456, 256, 0, stream>>>(W2, w2b, w2t);
  flow_kernel<<<BTOT / EPB, 512, SMEM_BYTES, stream>>>(
      y, Jp, W1, b1, b2, W3, b3, w2b, w2t, ws_sum, out);
  kl_kernel<<<64, 256, 0, stream>>>(y, Jp, Wsym, lvd, ws_sum, out + BTOT);
}

// Round 7
// 1985.986 us; speedup vs baseline: 1.8935x; 1.8935x over previous
//
#include <hip/hip_runtime.h>
#include <hip/hip_bf16.h>
#include <math.h>

#define BTOT   16384
#define NLAYER 24
#define HID    192
#define NDIN   12
#define NBASE  66
#define EPSP   1e-3f
#define EPB    16        // elements per block -> grid 1024

// ---------------- LDS layout (bytes), 62,240 total ----------------
#define EST 200          // j/k stride (shorts) for sH1b/sGb rows
#define OB_H1  0         // ushort[16*200]  6400 : h1 bf16 [e][k]
#define OB_G   6400      // ushort[96*200] 38400 : h2 (rows 0-15) then G [col][j]
#define OB_R   44800     // float[72*16]    4608 : cotangent rows [rt][e]
#define OB_W1  49408     // ushort[192*8]   3072 : W1 bf16 rows padded to 8
#define OB_W3  52480     // ushort[192*16]  6144 : W3 bf16 [j][t] rows padded 16
#define OB_PRM 58624     // float[12*16]     768 : prm sums; then tf@2i, es@2i+1
#define OB_GZ  59392     // float[6*96]     2304 : g_z1 sums [i][col] (atomics)
#define OB_Z1  61696     // float[6*16]      384 : z[6..12) for next F1
#define OB_LD  62080     // float[16]         64 : logdet acc
#define OB_ZQ  62144     // float[16]         64 : sum z^2
#define OB_RED 62208     // float[8]          32
#define SMEM_BYTES 62240

typedef __attribute__((ext_vector_type(8))) short s8v;
typedef __attribute__((ext_vector_type(4))) float f4v;
#define MFMA16(a,b,c) __builtin_amdgcn_mfma_f32_16x16x32_bf16(a,b,c,0,0,0)

__device__ __forceinline__ unsigned short f2bf(float f) {
  unsigned u = __builtin_bit_cast(unsigned, f);
  u += 0x7fffu + ((u >> 16) & 1u);          // RNE
  return (unsigned short)(u >> 16);
}
__device__ __forceinline__ float bf2f(unsigned short h) {
  unsigned u = ((unsigned)h) << 16;
  return __builtin_bit_cast(float, u);
}
__device__ __forceinline__ unsigned pk2(float a, float b) {
  return (unsigned)f2bf(a) | ((unsigned)f2bf(b) << 16);
}
__device__ __forceinline__ float blo(unsigned u) { return bf2f((unsigned short)(u & 0xffff)); }
__device__ __forceinline__ float bhi(unsigned u) { return bf2f((unsigned short)(u >> 16)); }

// ---------------------------------------------------------------------
// prep: W2 -> bf16 (orig layout) and bf16 transpose, into workspace.
__global__ void prep_kernel(const float* __restrict__ W2,
                            unsigned short* __restrict__ w2b,
                            unsigned short* __restrict__ w2t) {
  int idx = blockIdx.x * 256 + threadIdx.x;   // 884736 exact
  int l   = idx / (HID * HID);
  int rem = idx - l * HID * HID;
  int k   = rem / HID;
  int j   = rem - k * HID;
  w2b[idx] = f2bf(W2[idx]);                         // [l][j][k]
  w2t[idx] = f2bf(W2[l * HID * HID + j * HID + k]); // [l][k][j]
}

// ---------------------------------------------------------------------
// flow_kernel: block = 16 elements, 512 threads (8 waves), grid 1024.
// All 6 VJP cotangent rows are processed in ONE V2/V3/V5 phase per layer
// (rows are independent; only the layer loop is sequential).
// V3 GEMM: 192 k-rows x 96 cols (col = r*16+e) x 192 j. 12 m-tiles x 6
// n-tiles; wave w: mtg=(w&3)*3, ntg=(w>>2)*3 (3x3 tiles, acc=36 VGPR).
// NO min-blocks in launch_bounds: caps turn load-hoisting into spill
// (R5: (512,4)->291MB scratch; R6: (512,2)->808MB). Spill >> occupancy.
__global__ __launch_bounds__(512) void flow_kernel(
    float* __restrict__ yz, float* __restrict__ jp,
    const float* __restrict__ W1, const float* __restrict__ b1,
    const float* __restrict__ b2,
    const float* __restrict__ W3, const float* __restrict__ b3,
    const unsigned short* __restrict__ w2b,
    const unsigned short* __restrict__ w2t,
    float* __restrict__ ws_sum, float* __restrict__ out_lp) {
  extern __shared__ char smraw[];
  unsigned short* sH1b = (unsigned short*)(smraw + OB_H1);
  unsigned short* sGb  = (unsigned short*)(smraw + OB_G);
  unsigned short* sW3  = (unsigned short*)(smraw + OB_W3);
  float* sR   = (float*)(smraw + OB_R);
  float* sPRM = (float*)(smraw + OB_PRM);
  float* sGZ  = (float*)(smraw + OB_GZ);
  float* sZ1  = (float*)(smraw + OB_Z1);
  float* sLD  = (float*)(smraw + OB_LD);
  float* sZQ  = (float*)(smraw + OB_ZQ);
  float* sRed = (float*)(smraw + OB_RED);

  const int tid  = threadIdx.x;
  const int lane = tid & 63;
  const int w    = __builtin_amdgcn_readfirstlane(tid >> 6);
  const int e    = tid & 15;                     // element (scalar phases)
  const int s6   = (tid >> 4) * 6;               // 6-wide j slab (F1/S2/V2)
  const int lm   = lane & 15, lq = lane >> 4;    // MFMA lane coords
  const int mtg  = (w & 3) * 3;                  // m-tile base {0,3,6,9}
  const int ntg  = (w >> 2) * 3;                 // n-tile base {0,3}
  const int blk  = blockIdx.x;

  // ---- init ----
  float z_a = 0.f, z_b = 0.f;     // z[i], z[6+i] held by tid<96 (i=tid>>4)
  if (tid < 96) {
    int i = tid >> 4;
    z_a = yz[(blk * EPB + e) * 12 + i];
    z_b = yz[(blk * EPB + e) * 12 + 6 + i];
    sZ1[i * EPB + e] = z_b;
  }
  if (tid < 16) { sLD[tid] = 0.f; sZQ[tid] = 0.f; }
  if (tid == 0) sRed[0] = 0.f;
  if (tid >= 128 && tid < 128 + 576) sGZ[tid - 128] = 0.f;
  for (int idx = tid; idx < 72 * EPB; idx += 512) {
    int rt = idx >> 4, ee = idx & 15;
    sR[idx] = jp[(blk * EPB + ee) * 72 + rt];
  }
  __syncthreads();

  for (int l = NLAYER - 1; l >= 0; --l) {
    const float* W1l = W1 + l * HID * 6;
    const float* b1l = b1 + l * HID;
    const float* b2l = b2 + l * HID;
    const float* W3l = W3 + l * NDIN * HID;
    const float* b3l = b3 + l * NDIN;
    const unsigned short* w2bl = w2b + l * HID * HID;
    const unsigned short* w2tl = w2t + l * HID * HID;

    // ======== F1 phase: stage W1/W3 bf16, zero sPRM, h1 = relu(W1 z1+b1) =
    if (tid < 192) {
      const float* wr = W1l + tid * 6;
      uint4 pk;
      pk.x = pk2(wr[0], wr[1]); pk.y = pk2(wr[2], wr[3]);
      pk.z = pk2(wr[4], wr[5]); pk.w = 0;
      *(uint4*)(smraw + OB_W1 + tid * 16) = pk;
      // W3 [j][t] bf16, t-pairs packed
      unsigned* wd = (unsigned*)&sW3[tid * 16];
      #pragma unroll
      for (int c = 0; c < 6; ++c)
        wd[c] = pk2(W3l[(2 * c) * HID + tid], W3l[(2 * c + 1) * HID + tid]);
      sPRM[tid] = 0.f;
    }
    {
      float z1v[6];
      #pragma unroll
      for (int i = 0; i < 6; ++i) z1v[i] = sZ1[i * EPB + e];
      #pragma unroll
      for (int jj = 0; jj < 6; ++jj) {
        int j = s6 + jj;
        float acc = b1l[j];
        #pragma unroll
        for (int i = 0; i < 6; ++i) acc = fmaf(W1l[j * 6 + i], z1v[i], acc);
        sH1b[e * EST + j] = f2bf(fmaxf(acc, 0.f));
      }
    }
    __syncthreads();

    // ======== S1: F2 via MFMA (waves 0-3): h2 = relu(W2 h1+b2) -> rows 0-15
    if (w < 4) {
      f4v acc3[3] = {{0,0,0,0},{0,0,0,0},{0,0,0,0}};
      #pragma unroll 2
      for (int kk = 0; kk < 6; ++kk) {
        int jo = kk * 32 + lq * 8;
        s8v B = *(const s8v*)&sH1b[lm * EST + jo];
        #pragma unroll
        for (int p = 0; p < 3; ++p) {
          s8v A = *(const s8v*)(w2bl + ((mtg + p) * 16 + lm) * HID + jo);
          acc3[p] = MFMA16(A, B, acc3[p]);
        }
      }
      #pragma unroll
      for (int p = 0; p < 3; ++p) {
        int jb2 = (mtg + p) * 16 + lq * 4;
        float h0 = fmaxf(acc3[p][0] + b2l[jb2],     0.f);
        float h1 = fmaxf(acc3[p][1] + b2l[jb2 + 1], 0.f);
        float h2 = fmaxf(acc3[p][2] + b2l[jb2 + 2], 0.f);
        float h3 = fmaxf(acc3[p][3] + b2l[jb2 + 3], 0.f);
        unsigned* dst = (unsigned*)sGb + ((lm * EST + jb2) >> 1);
        dst[0] = pk2(h0, h1);
        dst[1] = pk2(h2, h3);
      }
    }
    __syncthreads();

    // ======== S2: prm partials (fp32 W3 from global) + wave-reduce ======
    {
      const unsigned* hp = (const unsigned*)&sGb[e * EST + s6];
      unsigned h2d0 = hp[0], h2d1 = hp[1], h2d2 = hp[2];
      float h2v[6] = { blo(h2d0), bhi(h2d0), blo(h2d1),
                       bhi(h2d1), blo(h2d2), bhi(h2d2) };
      #pragma unroll
      for (int t = 0; t < 12; ++t) {
        const float* w3r = W3l + t * HID + s6;
        float pp = 0.f;
        #pragma unroll
        for (int jj = 0; jj < 6; ++jj) pp = fmaf(w3r[jj], h2v[jj], pp);
        pp += __shfl_xor(pp, 16);
        pp += __shfl_xor(pp, 32);
        if (lane < 16) atomicAdd(&sPRM[t * EPB + lane], pp);
      }
    }
    __syncthreads();

    // ======== U: coupling update; sPRM becomes tf@(2i), es@(2i+1) ========
    if (tid < 96) {
      int i = tid >> 4;
      float sh = b3l[2 * i]     + sPRM[(2 * i) * EPB + e];
      float sr = b3l[2 * i + 1] + sPRM[(2 * i + 1) * EPB + e];
      float s  = 2.f * tanhf(0.5f * sr);
      float es = expf(s), en = expf(-s);
      float tv = z_a - sh;
      z_a = z_b;
      z_b = tv * en;
      sZ1[i * EPB + e] = z_b;
      sPRM[(2 * i) * EPB + e]     = tv * (1.f - 0.25f * s * s);  // tf
      sPRM[(2 * i + 1) * EPB + e] = es;                          // es
      atomicAdd(&sLD[e], -s);
    }
    __syncthreads();

    // ======== V2 (all 6 rows): G[col=r*16+e][j] = mask2 .* (W3^T gp_r) ===
    {
      const unsigned* hp = (const unsigned*)&sGb[e * EST + s6];
      unsigned h2d0 = hp[0], h2d1 = hp[1], h2d2 = hp[2];
      float tf[6];
      #pragma unroll
      for (int i = 0; i < 6; ++i) tf[i] = sPRM[(2 * i) * EPB + e];
      // weff[jj][c] = W3[2c][s6+jj] + tf[c]*W3[2c+1][s6+jj]  (bf16 W3)
      float weff[6][6];
      #pragma unroll
      for (int jj = 0; jj < 6; ++jj) {
        const unsigned* wd = (const unsigned*)&sW3[(s6 + jj) * 16];
        #pragma unroll
        for (int c = 0; c < 6; ++c) {
          unsigned wv = wd[c];
          weff[jj][c] = fmaf(tf[c], bhi(wv), blo(wv));
        }
      }
      #pragma unroll
      for (int r = 0; r < 6; ++r) {
        float g[6] = {0.f, 0.f, 0.f, 0.f, 0.f, 0.f};
        #pragma unroll
        for (int c = 0; c < 6; ++c) {
          float r1 = sR[(r * 12 + c) * EPB + e];
          #pragma unroll
          for (int jj = 0; jj < 6; ++jj)
            g[jj] = fmaf(weff[jj][c], r1, g[jj]);
        }
        unsigned* dst = (unsigned*)sGb + (((r * 16 + e) * EST + s6) >> 1);
        float v0 = (h2d0 & 0xffffu) ? g[0] : 0.f;
        float v1 = (h2d0 >> 16)     ? g[1] : 0.f;
        float v2 = (h2d1 & 0xffffu) ? g[2] : 0.f;
        float v3 = (h2d1 >> 16)     ? g[3] : 0.f;
        float v4 = (h2d2 & 0xffffu) ? g[4] : 0.f;
        float v5 = (h2d2 >> 16)     ? g[5] : 0.f;
        dst[0] = pk2(v0, v1); dst[1] = pk2(v2, v3); dst[2] = pk2(v4, v5);
      }
    }
    __syncthreads();

    // ======== V3 (all rows, one GEMM): D[k][col] = W2^T G; epi -> sGZ ====
    {
      f4v acc[3][3] = {{{0,0,0,0},{0,0,0,0},{0,0,0,0}},
                       {{0,0,0,0},{0,0,0,0},{0,0,0,0}},
                       {{0,0,0,0},{0,0,0,0},{0,0,0,0}}};
      #pragma unroll 2
      for (int kk = 0; kk < 6; ++kk) {
        int jo = kk * 32 + lq * 8;
        s8v A[3], B[3];
        #pragma unroll
        for (int p = 0; p < 3; ++p)
          A[p] = *(const s8v*)(w2tl + ((mtg + p) * 16 + lm) * HID + jo);
        #pragma unroll
        for (int q = 0; q < 3; ++q)
          B[q] = *(const s8v*)&sGb[((ntg + q) * 16 + lm) * EST + jo];
        #pragma unroll
        for (int p = 0; p < 3; ++p)
          #pragma unroll
          for (int q = 0; q < 3; ++q)
            acc[p][q] = MFMA16(A[p], B[q], acc[p][q]);
      }
      // epilogue: mask1 (e=lm, q-independent) + W1^T, accumulate pz[q][i]
      float pz[3][6];
      #pragma unroll
      for (int q = 0; q < 3; ++q)
        #pragma unroll
        for (int i = 0; i < 6; ++i) pz[q][i] = 0.f;
      #pragma unroll
      for (int p = 0; p < 3; ++p) {
        int kb = (mtg + p) * 16 + lq * 4;
        const unsigned* mp = (const unsigned*)&sH1b[lm * EST + kb];
        unsigned mm0 = mp[0], mm1 = mp[1];
        unsigned short hb[4] = {
          (unsigned short)(mm0 & 0xffff), (unsigned short)(mm0 >> 16),
          (unsigned short)(mm1 & 0xffff), (unsigned short)(mm1 >> 16)};
        #pragma unroll
        for (int rg = 0; rg < 4; ++rg) {
          uint4 wr = *(const uint4*)(smraw + OB_W1 + (kb + rg) * 16);
          float w10 = blo(wr.x), w11 = bhi(wr.x), w12 = blo(wr.y);
          float w13 = bhi(wr.y), w14 = blo(wr.z), w15 = bhi(wr.z);
          #pragma unroll
          for (int q = 0; q < 3; ++q) {
            float val = hb[rg] ? acc[p][q][rg] : 0.f;
            pz[q][0] = fmaf(w10, val, pz[q][0]);
            pz[q][1] = fmaf(w11, val, pz[q][1]);
            pz[q][2] = fmaf(w12, val, pz[q][2]);
            pz[q][3] = fmaf(w13, val, pz[q][3]);
            pz[q][4] = fmaf(w14, val, pz[q][4]);
            pz[q][5] = fmaf(w15, val, pz[q][5]);
          }
        }
      }
      // wave-reduce over lq (xor 16/32), then one atomic per (q,i) from lm lanes
      #pragma unroll
      for (int q = 0; q < 3; ++q)
        #pragma unroll
        for (int i = 0; i < 6; ++i) {
          float v = pz[q][i];
          v += __shfl_xor(v, 16);
          v += __shfl_xor(v, 32);
          if (lane < 16) atomicAdd(&sGZ[i * 96 + (ntg + q) * 16 + lane], v);
        }
    }
    __syncthreads();

    // ======== V5 (all rows): cotangent update; re-zero sGZ ==============
    for (int idx = tid; idx < 576; idx += 512) {
      int i   = idx / 96;            // 0..5
      int rem = idx - i * 96;        // r*16+e
      int r   = rem >> 4, e5 = rem & 15;
      float r1  = sR[(r * 12 + i) * EPB + e5];
      float r2o = sR[(r * 12 + 6 + i) * EPB + e5];
      float es  = sPRM[(2 * i + 1) * EPB + e5];
      sR[(r * 12 + i) * EPB + e5]     = r2o + sGZ[i * 96 + rem];
      sR[(r * 12 + 6 + i) * EPB + e5] = r1 * es;
      sGZ[i * 96 + rem] = 0.f;
    }
    __syncthreads();
  }

  // ---- epilogue ----
  if (tid < 96) {
    int i = tid >> 4;
    yz[(blk * EPB + e) * 12 + i]     = z_a;
    yz[(blk * EPB + e) * 12 + 6 + i] = z_b;
    atomicAdd(&sZQ[e], fmaf(z_a, z_a, z_b * z_b));
  }
  __syncthreads();
  if (tid < 16)
    out_lp[blk * EPB + tid] = sLD[tid] - 11.027262398456072f - 0.5f * sZQ[tid];

  float part = 0.f;
  for (int idx = tid; idx < 72 * EPB; idx += 512) {
    int rt = idx >> 4, ee = idx & 15;
    float v = sR[idx];
    jp[(blk * EPB + ee) * 72 + rt] = v;
    part = fmaf(v, v, part);
  }
  #pragma unroll
  for (int off = 32; off > 0; off >>= 1) part += __shfl_down(part, off, 64);
  if ((tid & 63) == 0) atomicAdd(&sRed[0], part);
  __syncthreads();
  if (tid == 0) atomicAdd(ws_sum, sRed[0]);
}

// ---------------------------------------------------------------------
// kl_kernel: one thread per element (unchanged from R3..R6 PASS).
__global__ __launch_bounds__(256) void kl_kernel(
    const float* __restrict__ zin, const float* __restrict__ jpin,
    const float* __restrict__ Wsym, const float* __restrict__ lvd,
    const float* __restrict__ ws_sum, float* __restrict__ out_kl) {
  int elem = blockIdx.x * 256 + threadIdx.x;
  float z[12];
  #pragma unroll
  for (int i = 0; i < 12; ++i) z[i] = zin[elem * 12 + i];
  float scale = 1.0f / sqrtf(ws_sum[0]);
  float Jp[6][12];
  #pragma unroll
  for (int n = 0; n < 6; ++n)
    #pragma unroll
    for (int j = 0; j < 12; ++j)
      Jp[n][j] = jpin[elem * 72 + n * 12 + j] * scale;

  float Sq[78];
  #pragma unroll
  for (int i = 0; i < 78; ++i) Sq[i] = 0.f;
  float tq = 0.f, tpq = 0.f;

  for (int m = 0; m < NBASE; ++m) {
    const float* Wm = Wsym + m * 144;
    float jq[12];
    #pragma unroll
    for (int j = 0; j < 12; ++j) {
      float acc = 0.f;
      #pragma unroll
      for (int i = 0; i < 12; ++i)
        acc = fmaf(Wm[j * 12 + i] - Wm[i * 12 + j], z[i], acc);
      jq[j] = acc;
    }
    #pragma unroll
    for (int i = 0; i < 12; ++i) {
      tq = fmaf(jq[i], jq[i], tq);
      #pragma unroll
      for (int j = 0; j <= i; ++j)
        Sq[i * (i + 1) / 2 + j] = fmaf(jq[i], jq[j], Sq[i * (i + 1) / 2 + j]);
    }
    #pragma unroll
    for (int n = 0; n < 6; ++n) {
      float d = 0.f;
      #pragma unroll
      for (int j = 0; j < 12; ++j) d = fmaf(Jp[n][j], jq[j], d);
      tpq = fmaf(d, d, tpq);
    }
  }

  float Dv[12], Db[12];
  #pragma unroll
  for (int j = 0; j < 12; ++j) Dv[j] = expf(-lvd[j]);

  float mh = 0.f;
  #pragma unroll
  for (int i = 0; i < 12; ++i) mh += Sq[i * (i + 1) / 2 + i] + Dv[i];
  float norm_H = fmaxf(mh * (1.f / 12.f), 1e-6f);
  #pragma unroll
  for (int i = 0; i < 12; ++i) Sq[i * (i + 1) / 2 + i] += Dv[i] + 1e-3f * norm_H;
  float sumDb = 0.f;
  #pragma unroll
  for (int j = 0; j < 12; ++j) { Db[j] = Dv[j] + 1e-3f * norm_H; sumDb += Db[j]; }

  float M[21];
  #pragma unroll
  for (int n = 0; n < 6; ++n)
    #pragma unroll
    for (int mm = 0; mm <= n; ++mm) {
      float acc = 0.f;
      #pragma unroll
      for (int j = 0; j < 12; ++j) acc = fmaf(Jp[n][j], Jp[mm][j], acc);
      M[n * (n + 1) / 2 + mm] = acc;
    }
  float md = 0.f;
  #pragma unroll
  for (int i = 0; i < 6; ++i) md += M[i * (i + 1) / 2 + i];
  float norm_M = fmaxf(md * (1.f / 6.f) + EPSP, 1e-6f);
  #pragma unroll
  for (int i = 0; i < 6; ++i) M[i * (i + 1) / 2 + i] += EPSP + 1e-3f * norm_M;

  float trace_p = 0.f;
  #pragma unroll
  for (int n = 0; n < 6; ++n)
    #pragma unroll
    for (int j = 0; j < 12; ++j)
      trace_p = fmaf(Jp[n][j] * Jp[n][j], Db[j], trace_p);

  float trace = (EPSP + 1e-3f * norm_M) * (sumDb + tq) + trace_p + tpq;

  float ldM = 0.f;
  #pragma unroll
  for (int jc = 0; jc < 6; ++jc) {
    float d = M[jc * (jc + 1) / 2 + jc];
    #pragma unroll
    for (int k = 0; k < jc; ++k) d -= M[jc * (jc + 1) / 2 + k] * M[jc * (jc + 1) / 2 + k];
    d = sqrtf(d);
    ldM += logf(d);
    float di = 1.f / d;
    M[jc * (jc + 1) / 2 + jc] = d;
    #pragma unroll
    for (int i2 = jc + 1; i2 < 6; ++i2) {
      float v = M[i2 * (i2 + 1) / 2 + jc];
      #pragma unroll
      for (int k = 0; k < jc; ++k) v -= M[i2 * (i2 + 1) / 2 + k] * M[jc * (jc + 1) / 2 + k];
      M[i2 * (i2 + 1) / 2 + jc] = v * di;
    }
  }

  float ldH = 0.f;
  #pragma unroll
  for (int jc = 0; jc < 12; ++jc) {
    float d = Sq[jc * (jc + 1) / 2 + jc];
    #pragma unroll
    for (int k = 0; k < jc; ++k) d -= Sq[jc * (jc + 1) / 2 + k] * Sq[jc * (jc + 1) / 2 + k];
    d = sqrtf(d);
    ldH += logf(d);
    float di = 1.f / d;
    Sq[jc * (jc + 1) / 2 + jc] = d;
    #pragma unroll
    for (int i2 = jc + 1; i2 < 12; ++i2) {
      float v = Sq[i2 * (i2 + 1) / 2 + jc];
      #pragma unroll
      for (int k = 0; k < jc; ++k) v -= Sq[i2 * (i2 + 1) / 2 + k] * Sq[jc * (jc + 1) / 2 + k];
      Sq[i2 * (i2 + 1) / 2 + jc] = v * di;
    }
  }

  float logdet_p = 2.f * ldM + 6.f * logf(EPSP);
  float logdet_q = 2.f * ldH;
  out_kl[elem] = 0.5f * (trace - (logdet_p + logdet_q) - 12.f);
}

// ---------------------------------------------------------------------
extern "C" void kernel_launch(void* const* d_in, const int* in_sizes, int n_in,
                              void* d_out, int out_size, void* d_ws, size_t ws_size,
                              hipStream_t stream) {
  (void)in_sizes; (void)n_in; (void)out_size; (void)ws_size;
  float* y    = (float*)d_in[0];   // consumed, then overwritten with z
  float* Jp   = (float*)d_in[1];   // consumed, then overwritten with pullback Jp
  const float* W1   = (const float*)d_in[2];
  const float* b1   = (const float*)d_in[3];
  const float* W2   = (const float*)d_in[4];
  const float* b2   = (const float*)d_in[5];
  const float* W3   = (const float*)d_in[6];
  const float* b3   = (const float*)d_in[7];
  const float* Wsym = (const float*)d_in[8];
  const float* lvd  = (const float*)d_in[9];
  float* out = (float*)d_out;      // fp32: [log_prob (B), kl (B)]

  float* ws_sum = (float*)d_ws;
  unsigned short* w2b = (unsigned short*)((char*)d_ws + 256);
  unsigned short* w2t = (unsigned short*)((char*)d_ws + 256 +
                                          NLAYER * HID * HID * 2);
  hipMemsetAsync(d_ws, 0, 4, stream);

  hipFuncSetAttribute((const void*)flow_kernel,
                      hipFuncAttributeMaxDynamicSharedMemorySize, SMEM_BYTES);

  prep_kernel<<<3456, 256, 0, stream>>>(W2, w2b, w2t);
  flow_kernel<<<BTOT / EPB, 512, SMEM_BYTES, stream>>>(
      y, Jp, W1, b1, b2, W3, b3, w2b, w2t, ws_sum, out);
  kl_kernel<<<64, 256, 0, stream>>>(y, Jp, Wsym, lvd, ws_sum, out + BTOT);
}